// Round 2
// baseline (1239.497 us; speedup 1.0000x reference)
//
#include <hip/hip_runtime.h>

#define B_ 16
#define C_ 192
#define T_ 2048
#define F_ 256
#define HALF_ 96

typedef short s16x8 __attribute__((ext_vector_type(8)));
typedef float f32x4 __attribute__((ext_vector_type(4)));
typedef unsigned short ushort;

__device__ __forceinline__ float gelu_f(float x) {
  return 0.5f * x * (1.f + erff(x * 0.70710678118654752f));
}

__device__ __forceinline__ ushort f2bf(float f) {
  unsigned u = __float_as_uint(f);
  unsigned r = u + 0x7fff + ((u >> 16) & 1);
  return (ushort)(r >> 16);
}
__device__ __forceinline__ float bf2f(ushort h) {
  return __uint_as_float(((unsigned)h) << 16);
}

// ---------------------------------------------------------------------------
// K1: h[b,f,t] = pre_w[f,:] @ x0[b,:,t] + pre_b[f]
// ---------------------------------------------------------------------------
__global__ void pre_gemm_k(const float* __restrict__ x,
                           const float* __restrict__ pw,
                           const float* __restrict__ pb,
                           float* __restrict__ h) {
  int t = blockIdx.x * 256 + threadIdx.x;
  int f0 = blockIdx.y * 8;
  int b = blockIdx.z;
  float acc[8];
#pragma unroll
  for (int j = 0; j < 8; ++j) acc[j] = pb[f0 + j];
  const float* xp = x + ((size_t)b * C_) * T_ + t;
  const float* wp = pw + (size_t)f0 * HALF_;
#pragma unroll 4
  for (int c = 0; c < HALF_; ++c) {
    float xv = xp[(size_t)c * T_];
#pragma unroll
    for (int j = 0; j < 8; ++j)
      acc[j] = fmaf(wp[j * HALF_ + c], xv, acc[j]);
  }
  float* hp = h + ((size_t)b * F_ + f0) * T_ + t;
#pragma unroll
  for (int j = 0; j < 8; ++j) hp[(size_t)j * T_] = acc[j];
}

// ---------------------------------------------------------------------------
// K2: one layer. SPLIT_OUT=false: h_out fp32 [b][c][t].
//     SPLIT_OUT=true: (h*mask) as bf16 hi/lo, TRANSPOSED [b][t][c].
// ---------------------------------------------------------------------------
template <bool SPLIT_OUT>
__global__ __launch_bounds__(256, 2) void layer_k(
    const float* __restrict__ h_in, float* __restrict__ h_out,
    ushort* __restrict__ hi_out, ushort* __restrict__ lo_out,
    const float* __restrict__ mask,
    const float* __restrict__ dww, const float* __restrict__ dwb,
    const float* __restrict__ g1, const float* __restrict__ b1,
    const float* __restrict__ pww, const float* __restrict__ pwb,
    const float* __restrict__ g2, const float* __restrict__ b2,
    int dil) {
  __shared__ float y1[F_ * 68];
  __shared__ float redA[8 * 64];
  __shared__ float stat[2 * 64];
  int tid = threadIdx.x;
  int b = blockIdx.y;
  int t0 = blockIdx.x * 64;

  // ---- Phase A: depthwise conv (+bias) + partial channel stats ----
  {
    int t = tid & 63, cg = tid >> 6;
    int tz = t0 + t;
    int tm = tz - dil, tp = tz + dil;
    bool vm = (tm >= 0), vp = (tp < T_);
    float mm = vm ? mask[b * T_ + tm] : 0.f;
    float mz = mask[b * T_ + tz];
    float mp = vp ? mask[b * T_ + tp] : 0.f;
    const float* hb = h_in + ((size_t)b * F_) * T_;
    float s = 0.f, q = 0.f;
#pragma unroll 4
    for (int k = 0; k < 64; ++k) {
      int c = cg * 64 + k;
      const float* hr = hb + (size_t)c * T_;
      float v0 = vm ? hr[tm] * mm : 0.f;
      float v1 = hr[tz] * mz;
      float v2 = vp ? hr[tp] * mp : 0.f;
      float v = fmaf(dww[c * 3], v0,
                fmaf(dww[c * 3 + 1], v1,
                fmaf(dww[c * 3 + 2], v2, dwb[c])));
      y1[c * 68 + t] = v;
      s += v;
      q = fmaf(v, v, q);
    }
    redA[cg * 64 + t] = s;
    redA[256 + cg * 64 + t] = q;
  }
  __syncthreads();
  if (tid < 64) {
    float s = redA[tid] + redA[64 + tid] + redA[128 + tid] + redA[192 + tid];
    float q = redA[256 + tid] + redA[320 + tid] + redA[384 + tid] + redA[448 + tid];
    float mean = s * (1.f / 256.f);
    float var = q * (1.f / 256.f) - mean * mean;
    stat[tid] = mean;
    stat[64 + tid] = rsqrtf(var + 1e-5f);
  }
  __syncthreads();
  {
    int t = tid & 63, cg = tid >> 6;
    float mean = stat[t], rstd = stat[64 + t];
#pragma unroll 4
    for (int k = 0; k < 64; ++k) {
      int c = cg * 64 + k;
      float v = y1[c * 68 + t];
      v = (v - mean) * rstd * g1[c] + b1[c];
      y1[c * 68 + t] = gelu_f(v);
    }
  }
  __syncthreads();
  // ---- Phase B: pointwise GEMM 256x256, tile 8o x 8t ----
  int og = tid >> 3, tg = tid & 7;
  int o0 = og * 8, tb = tg * 8;
  float acc[8][8];
#pragma unroll
  for (int j = 0; j < 8; ++j) {
    float pv = pwb[o0 + j];
#pragma unroll
    for (int k = 0; k < 8; ++k) acc[j][k] = pv;
  }
#pragma unroll 1
  for (int c = 0; c < F_; c += 4) {
    float4 w4[8];
#pragma unroll
    for (int j = 0; j < 8; ++j)
      w4[j] = *(const float4*)(pww + (size_t)(o0 + j) * F_ + c);
#pragma unroll
    for (int cc = 0; cc < 4; ++cc) {
      float4 xlo = *(const float4*)&y1[(c + cc) * 68 + tb];
      float4 xhi = *(const float4*)&y1[(c + cc) * 68 + tb + 4];
#pragma unroll
      for (int j = 0; j < 8; ++j) {
        float w = cc == 0 ? w4[j].x : cc == 1 ? w4[j].y : cc == 2 ? w4[j].z : w4[j].w;
        acc[j][0] = fmaf(w, xlo.x, acc[j][0]);
        acc[j][1] = fmaf(w, xlo.y, acc[j][1]);
        acc[j][2] = fmaf(w, xlo.z, acc[j][2]);
        acc[j][3] = fmaf(w, xlo.w, acc[j][3]);
        acc[j][4] = fmaf(w, xhi.x, acc[j][4]);
        acc[j][5] = fmaf(w, xhi.y, acc[j][5]);
        acc[j][6] = fmaf(w, xhi.z, acc[j][6]);
        acc[j][7] = fmaf(w, xhi.w, acc[j][7]);
      }
    }
  }
  __syncthreads();
  // ---- Phase C: channel stats of y2 ----
  float* redC = y1;
#pragma unroll
  for (int k = 0; k < 8; ++k) {
    float s = 0.f, q = 0.f;
#pragma unroll
    for (int j = 0; j < 8; ++j) {
      float v = acc[j][k];
      s += v;
      q = fmaf(v, v, q);
    }
    redC[og * 65 + tb + k] = s;
    redC[32 * 65 + og * 65 + tb + k] = q;
  }
  __syncthreads();
  if (tid < 64) {
    float s = 0.f, q = 0.f;
#pragma unroll
    for (int g = 0; g < 32; ++g) {
      s += redC[g * 65 + tid];
      q += redC[32 * 65 + g * 65 + tid];
    }
    float mean = s * (1.f / 256.f);
    float var = q * (1.f / 256.f) - mean * mean;
    stat[tid] = mean;
    stat[64 + tid] = rsqrtf(var + 1e-5f);
  }
  __syncthreads();
  // ---- normalize + gelu + residual ----
  const float* hbr = h_in + ((size_t)b * F_) * T_ + t0;
#pragma unroll
  for (int j = 0; j < 8; ++j) {
    int o = o0 + j;
    float gg = g2[o], bb = b2[o];
    float4 r0 = *(const float4*)(hbr + (size_t)o * T_ + tb);
    float4 r1 = *(const float4*)(hbr + (size_t)o * T_ + tb + 4);
    float rr[8] = {r0.x, r0.y, r0.z, r0.w, r1.x, r1.y, r1.z, r1.w};
#pragma unroll
    for (int k = 0; k < 8; ++k) {
      int t = tb + k;
      float u = (acc[j][k] - stat[t]) * stat[64 + t] * gg + bb;
      acc[j][k] = rr[k] + gelu_f(u);
    }
  }
  if (!SPLIT_OUT) {
    float* ho = h_out + ((size_t)b * F_) * T_ + t0;
#pragma unroll
    for (int j = 0; j < 8; ++j) {
      int o = o0 + j;
      float4 w0 = make_float4(acc[j][0], acc[j][1], acc[j][2], acc[j][3]);
      float4 w1 = make_float4(acc[j][4], acc[j][5], acc[j][6], acc[j][7]);
      *(float4*)(h_out + ((size_t)b * F_ + o) * T_ + t0 + tb) = w0;
      *(float4*)(h_out + ((size_t)b * F_ + o) * T_ + t0 + tb + 4) = w1;
    }
    (void)ho;
  } else {
    // write (h*mask) transposed as bf16 hi/lo: [b][t][c]
#pragma unroll
    for (int k = 0; k < 8; ++k) {
      int t = t0 + tb + k;
      float mv = mask[(size_t)b * T_ + t];
      ushort hv[8], lv[8];
#pragma unroll
      for (int j = 0; j < 8; ++j) {
        float v = acc[j][k] * mv;
        ushort h16 = f2bf(v);
        hv[j] = h16;
        lv[j] = f2bf(v - bf2f(h16));
      }
      size_t base = ((size_t)b * T_ + t) * F_ + o0;
      *(uint4*)(hi_out + base) = *(const uint4*)hv;
      *(uint4*)(lo_out + base) = *(const uint4*)lv;
    }
  }
}

// ---------------------------------------------------------------------------
// K-wsplit: proj_w fp32 -> bf16 hi/lo (same [row][k] layout)
// ---------------------------------------------------------------------------
__global__ void wsplit_k(const float* __restrict__ w,
                         ushort* __restrict__ whi, ushort* __restrict__ wlo,
                         int n) {
  int i = blockIdx.x * 256 + threadIdx.x;
  if (i >= n) return;
  float v = w[i];
  ushort h16 = f2bf(v);
  whi[i] = h16;
  wlo[i] = f2bf(v - bf2f(h16));
}

// ---------------------------------------------------------------------------
// K3: proj GEMM via split-bf16 MFMA + RQ spline + logdet
// grid (T/64, 12, B); block 256 (4 waves). Per block: M=232(pad240), N=64,
// K=256 staged in two 128-halves. Wave w owns n-tile w (16 t), 15 m-tiles.
// ---------------------------------------------------------------------------
__global__ __launch_bounds__(256, 2) void proj_spline_k(
    const ushort* __restrict__ h_hi, const ushort* __restrict__ h_lo,
    const float* __restrict__ x, const float* __restrict__ mask,
    const ushort* __restrict__ w_hi, const ushort* __restrict__ w_lo,
    const float* __restrict__ pb,
    float* __restrict__ out, float* __restrict__ logdet) {
  // union: B-staging (2 comps x 64 x 136 bf16 = 34816 B) / s-tile (232x66 f32)
  __shared__ __align__(16) char smem[232 * 66 * 4];
  __shared__ float red[4];
  ushort* bh_lds = (ushort*)smem;             // [64][136]
  ushort* bl_lds = (ushort*)(smem + 64 * 136 * 2);
  float* s_lds = (float*)smem;                // [232][66] (after GEMM)

  int tid = threadIdx.x;
  int t0 = blockIdx.x * 64;
  int chunk = blockIdx.y;
  int b = blockIdx.z;
  int lane = tid & 63;
  int wid = tid >> 6;
  int col = lane & 15;     // n within n-tile / m within a-row-group
  int quad = lane >> 4;
  int n0 = wid * 16;

  f32x4 acc[15];
#pragma unroll
  for (int mt = 0; mt < 15; ++mt) acc[mt] = (f32x4)(0.f);

  int wrow = chunk * 232 + col;  // + mt*16 gives A row

#pragma unroll 1
  for (int khalf = 0; khalf < 2; ++khalf) {
    // ---- stage B half: h_hi/h_lo [b][t0+t][khalf*128 + k] -> lds [t][k] ----
#pragma unroll
    for (int p = 0; p < 4; ++p) {
      int idx = tid + p * 256;       // 1024 chunks of 16B per component
      int row = idx >> 4;
      int u = idx & 15;
      size_t gs = ((size_t)(b * T_ + t0 + row)) * F_ + khalf * 128 + u * 8;
      *(uint4*)(bh_lds + row * 136 + u * 8) = *(const uint4*)(h_hi + gs);
      *(uint4*)(bl_lds + row * 136 + u * 8) = *(const uint4*)(h_lo + gs);
    }
    __syncthreads();
#pragma unroll
    for (int ks = 0; ks < 4; ++ks) {
      int kloc = ks * 32 + quad * 8;
      s16x8 bh = *(const s16x8*)(bh_lds + (n0 + col) * 136 + kloc);
      s16x8 bl = *(const s16x8*)(bl_lds + (n0 + col) * 136 + kloc);
      int kglob = khalf * 128 + kloc;
#pragma unroll
      for (int mt = 0; mt < 15; ++mt) {
        int rowA = wrow + mt * 16;
        rowA = rowA > 2783 ? 2783 : rowA;
        size_t off = (size_t)rowA * F_ + kglob;
        s16x8 ah = *(const s16x8*)(w_hi + off);
        s16x8 al = *(const s16x8*)(w_lo + off);
        acc[mt] = __builtin_amdgcn_mfma_f32_16x16x32_bf16(ah, bh, acc[mt], 0, 0, 0);
        acc[mt] = __builtin_amdgcn_mfma_f32_16x16x32_bf16(al, bh, acc[mt], 0, 0, 0);
        acc[mt] = __builtin_amdgcn_mfma_f32_16x16x32_bf16(ah, bl, acc[mt], 0, 0, 0);
      }
    }
    __syncthreads();
  }
  // ---- write s-tile: s[local_row][t] = (acc + bias) * mask ----
  {
    float mval = mask[(size_t)b * T_ + t0 + n0 + col];
#pragma unroll
    for (int mt = 0; mt < 15; ++mt) {
#pragma unroll
      for (int r = 0; r < 4; ++r) {
        int local = mt * 16 + quad * 4 + r;
        if (local < 232)
          s_lds[local * 66 + n0 + col] = (acc[mt][r] + pb[chunk * 232 + local]) * mval;
      }
    }
  }
  __syncthreads();
  // ---- spline: 8 ch x 64 t per block; 2 elements per thread ----
  float lad_sum = 0.f;
  int ch_i = tid >> 5, ti = tid & 31;
  int ch = chunk * 8 + ch_i;
#pragma unroll 1
  for (int pass = 0; pass < 2; ++pass) {
    int t = ti + pass * 32;
    float s[29];
#pragma unroll
    for (int j = 0; j < 29; ++j) s[j] = s_lds[(ch_i * 29 + j) * 66 + t];
    float xin = x[((size_t)b * C_ + HALF_ + ch) * T_ + t0 + t];
    float mval = mask[(size_t)b * T_ + t0 + t];
    float uw[10];
    float mx = -1e30f;
#pragma unroll
    for (int j = 0; j < 10; ++j) { uw[j] = s[j] * 0.0625f; mx = fmaxf(mx, uw[j]); }
    float ew[10]; float esum = 0.f;
#pragma unroll
    for (int j = 0; j < 10; ++j) { ew[j] = expf(uw[j] - mx); esum += ew[j]; }
    float inv = 1.f / esum;
    float cw[11];
    cw[0] = -5.f;
    float csum = 0.f;
#pragma unroll
    for (int j = 0; j < 9; ++j) {
      csum += fmaf(0.99f, ew[j] * inv, 0.001f);
      cw[j + 1] = fmaf(10.f, csum, -5.f);
    }
    cw[10] = 5.f;
    float uh[10]; mx = -1e30f;
#pragma unroll
    for (int j = 0; j < 10; ++j) { uh[j] = s[10 + j] * 0.0625f; mx = fmaxf(mx, uh[j]); }
    float eh[10]; esum = 0.f;
#pragma unroll
    for (int j = 0; j < 10; ++j) { eh[j] = expf(uh[j] - mx); esum += eh[j]; }
    inv = 1.f / esum;
    float chh[11];
    chh[0] = -5.f;
    csum = 0.f;
#pragma unroll
    for (int j = 0; j < 9; ++j) {
      csum += fmaf(0.99f, eh[j] * inv, 0.001f);
      chh[j + 1] = fmaf(10.f, csum, -5.f);
    }
    chh[10] = 5.f;
    float dv[11];
    dv[0] = 1.f; dv[10] = 1.f;
#pragma unroll
    for (int j = 1; j < 10; ++j) {
      float u = s[19 + j];
      float sp = (u > 15.f) ? u : log1pf(expf(u));
      dv[j] = 0.001f + sp;
    }
    float xc = fminf(fmaxf(xin, -5.f), 5.f);
    bool inside = (xin >= -5.f) && (xin <= 5.f);
    int idx = 0;
#pragma unroll
    for (int k = 1; k <= 10; ++k) idx += (xc >= cw[k]) ? 1 : 0;
    idx = idx > 9 ? 9 : idx;
    float in_cw = cw[0], in_w = cw[1] - cw[0];
    float in_ch = chh[0], in_h = chh[1] - chh[0];
    float d0 = dv[0], d1 = dv[1];
#pragma unroll
    for (int k = 1; k < 10; ++k) {
      bool sel = (idx == k);
      in_cw = sel ? cw[k] : in_cw;
      in_w = sel ? (cw[k + 1] - cw[k]) : in_w;
      in_ch = sel ? chh[k] : in_ch;
      in_h = sel ? (chh[k + 1] - chh[k]) : in_h;
      d0 = sel ? dv[k] : d0;
      d1 = sel ? dv[k + 1] : d1;
    }
    float theta = (xc - in_cw) / in_w;
    float delta = in_h / in_w;
    float omt = 1.f - theta;
    float t1m = theta * omt;
    float th2 = theta * theta;
    float denom = delta + (d0 + d1 - 2.f * delta) * t1m;
    float num = in_h * (delta * th2 + d0 * t1m);
    float outv = in_ch + num / denom;
    float dnum = delta * delta * (d1 * th2 + 2.f * delta * t1m + d0 * omt * omt);
    float lad = logf(dnum) - 2.f * logf(denom);
    float res = inside ? outv : xin;
    float ladv = inside ? lad : 0.f;
    out[((size_t)b * C_ + HALF_ + ch) * T_ + t0 + t] = res * mval;
    lad_sum += ladv * mval;
  }
#pragma unroll
  for (int off = 32; off > 0; off >>= 1)
    lad_sum += __shfl_down(lad_sum, off, 64);
  if ((tid & 63) == 0) red[tid >> 6] = lad_sum;
  __syncthreads();
  if (tid == 0)
    atomicAdd(logdet + b, red[0] + red[1] + red[2] + red[3]);
}

// ---------------------------------------------------------------------------
// K4: out[:, :96, :] = x0 * mask
// ---------------------------------------------------------------------------
__global__ void copy_x0_k(const float* __restrict__ x,
                          const float* __restrict__ mask,
                          float* __restrict__ out) {
  int i = blockIdx.x * 256 + threadIdx.x;
  int b = i / (HALF_ * T_ / 4);
  int r = i - b * (HALF_ * T_ / 4);
  int t4 = r & (T_ / 4 - 1);
  float4 v = ((const float4*)(x + (size_t)b * C_ * T_))[r];
  float4 m = ((const float4*)(mask + (size_t)b * T_))[t4];
  v.x *= m.x; v.y *= m.y; v.z *= m.z; v.w *= m.w;
  ((float4*)(out + (size_t)b * C_ * T_))[r] = v;
}

extern "C" void kernel_launch(void* const* d_in, const int* in_sizes, int n_in,
                              void* d_out, int out_size, void* d_ws, size_t ws_size,
                              hipStream_t stream) {
  const float* x      = (const float*)d_in[0];
  const float* mask   = (const float*)d_in[1];
  const float* pre_w  = (const float*)d_in[2];
  const float* pre_b  = (const float*)d_in[3];
  const float* dw_w   = (const float*)d_in[4];
  const float* dw_b   = (const float*)d_in[5];
  const float* pw_w   = (const float*)d_in[6];
  const float* pw_b   = (const float*)d_in[7];
  const float* g1     = (const float*)d_in[8];
  const float* b1     = (const float*)d_in[9];
  const float* g2     = (const float*)d_in[10];
  const float* b2     = (const float*)d_in[11];
  const float* proj_w = (const float*)d_in[12];
  const float* proj_b = (const float*)d_in[13];
  float* out = (float*)d_out;
  float* logdet = out + (size_t)B_ * C_ * T_;
  float* hA = (float*)d_ws;                      // 33.55 MB
  float* hB = hA + (size_t)B_ * F_ * T_;         // 33.55 MB
  // after layer3: hB region holds h split (hi, lo transposed bf16),
  //               hA region is free -> w split lives there
  ushort* h_hi = (ushort*)hB;
  ushort* h_lo = h_hi + (size_t)B_ * T_ * F_;
  ushort* w_hi = (ushort*)hA;
  ushort* w_lo = w_hi + 2784 * 256;

  hipMemsetAsync(logdet, 0, B_ * sizeof(float), stream);
  pre_gemm_k<<<dim3(T_ / 256, F_ / 8, B_), 256, 0, stream>>>(x, pre_w, pre_b, hA);
  layer_k<false><<<dim3(T_ / 64, B_), 256, 0, stream>>>(hA, hB, nullptr, nullptr,
      mask, dw_w, dw_b, g1, b1, pw_w, pw_b, g2, b2, 1);
  layer_k<false><<<dim3(T_ / 64, B_), 256, 0, stream>>>(hB, hA, nullptr, nullptr,
      mask, dw_w + F_ * 3, dw_b + F_, g1 + F_, b1 + F_,
      pw_w + F_ * F_, pw_b + F_, g2 + F_, b2 + F_, 3);
  layer_k<true><<<dim3(T_ / 64, B_), 256, 0, stream>>>(hA, nullptr, h_hi, h_lo,
      mask, dw_w + 2 * F_ * 3, dw_b + 2 * F_, g1 + 2 * F_, b1 + 2 * F_,
      pw_w + 2 * F_ * F_, pw_b + 2 * F_, g2 + 2 * F_, b2 + 2 * F_, 9);
  wsplit_k<<<dim3((2784 * 256 + 255) / 256), 256, 0, stream>>>(proj_w, w_hi, w_lo,
      2784 * 256);
  copy_x0_k<<<dim3(B_ * HALF_ * T_ / 4 / 256), 256, 0, stream>>>(x, mask, out);
  proj_spline_k<<<dim3(T_ / 64, 12, B_), 256, 0, stream>>>(h_hi, h_lo, x, mask,
      w_hi, w_lo, proj_b, out, logdet);
}

// Round 3
// 913.380 us; speedup vs baseline: 1.3570x; 1.3570x over previous
//
#include <hip/hip_runtime.h>

#define B_ 16
#define C_ 192
#define T_ 2048
#define F_ 256
#define HALF_ 96

typedef short s16x8 __attribute__((ext_vector_type(8)));
typedef float f32x4 __attribute__((ext_vector_type(4)));
typedef unsigned short ushort;

__device__ __forceinline__ float gelu_f(float x) {
  return 0.5f * x * (1.f + erff(x * 0.70710678118654752f));
}

__device__ __forceinline__ ushort f2bf(float f) {
  unsigned u = __float_as_uint(f);
  unsigned r = u + 0x7fff + ((u >> 16) & 1);
  return (ushort)(r >> 16);
}
__device__ __forceinline__ float bf2f(ushort h) {
  return __uint_as_float(((unsigned)h) << 16);
}

// ---------------------------------------------------------------------------
// K1: h[b,f,t] = pre_w[f,:] @ x0[b,:,t] + pre_b[f]
// ---------------------------------------------------------------------------
__global__ void pre_gemm_k(const float* __restrict__ x,
                           const float* __restrict__ pw,
                           const float* __restrict__ pb,
                           float* __restrict__ h) {
  int t = blockIdx.x * 256 + threadIdx.x;
  int f0 = blockIdx.y * 8;
  int b = blockIdx.z;
  float acc[8];
#pragma unroll
  for (int j = 0; j < 8; ++j) acc[j] = pb[f0 + j];
  const float* xp = x + ((size_t)b * C_) * T_ + t;
  const float* wp = pw + (size_t)f0 * HALF_;
#pragma unroll 4
  for (int c = 0; c < HALF_; ++c) {
    float xv = xp[(size_t)c * T_];
#pragma unroll
    for (int j = 0; j < 8; ++j)
      acc[j] = fmaf(wp[j * HALF_ + c], xv, acc[j]);
  }
  float* hp = h + ((size_t)b * F_ + f0) * T_ + t;
#pragma unroll
  for (int j = 0; j < 8; ++j) hp[(size_t)j * T_] = acc[j];
}

// ---------------------------------------------------------------------------
// K2: one layer. SPLIT_OUT=false: h_out fp32 [b][c][t].
//     SPLIT_OUT=true: (h*mask) as bf16 hi/lo, TRANSPOSED [b][t][c].
// ---------------------------------------------------------------------------
template <bool SPLIT_OUT>
__global__ __launch_bounds__(256, 2) void layer_k(
    const float* __restrict__ h_in, float* __restrict__ h_out,
    ushort* __restrict__ hi_out, ushort* __restrict__ lo_out,
    const float* __restrict__ mask,
    const float* __restrict__ dww, const float* __restrict__ dwb,
    const float* __restrict__ g1, const float* __restrict__ b1,
    const float* __restrict__ pww, const float* __restrict__ pwb,
    const float* __restrict__ g2, const float* __restrict__ b2,
    int dil) {
  __shared__ float y1[F_ * 68];
  __shared__ float redA[8 * 64];
  __shared__ float stat[2 * 64];
  int tid = threadIdx.x;
  int b = blockIdx.y;
  int t0 = blockIdx.x * 64;

  // ---- Phase A: depthwise conv (+bias) + partial channel stats ----
  {
    int t = tid & 63, cg = tid >> 6;
    int tz = t0 + t;
    int tm = tz - dil, tp = tz + dil;
    bool vm = (tm >= 0), vp = (tp < T_);
    float mm = vm ? mask[b * T_ + tm] : 0.f;
    float mz = mask[b * T_ + tz];
    float mp = vp ? mask[b * T_ + tp] : 0.f;
    const float* hb = h_in + ((size_t)b * F_) * T_;
    float s = 0.f, q = 0.f;
#pragma unroll 4
    for (int k = 0; k < 64; ++k) {
      int c = cg * 64 + k;
      const float* hr = hb + (size_t)c * T_;
      float v0 = vm ? hr[tm] * mm : 0.f;
      float v1 = hr[tz] * mz;
      float v2 = vp ? hr[tp] * mp : 0.f;
      float v = fmaf(dww[c * 3], v0,
                fmaf(dww[c * 3 + 1], v1,
                fmaf(dww[c * 3 + 2], v2, dwb[c])));
      y1[c * 68 + t] = v;
      s += v;
      q = fmaf(v, v, q);
    }
    redA[cg * 64 + t] = s;
    redA[256 + cg * 64 + t] = q;
  }
  __syncthreads();
  if (tid < 64) {
    float s = redA[tid] + redA[64 + tid] + redA[128 + tid] + redA[192 + tid];
    float q = redA[256 + tid] + redA[320 + tid] + redA[384 + tid] + redA[448 + tid];
    float mean = s * (1.f / 256.f);
    float var = q * (1.f / 256.f) - mean * mean;
    stat[tid] = mean;
    stat[64 + tid] = rsqrtf(var + 1e-5f);
  }
  __syncthreads();
  {
    int t = tid & 63, cg = tid >> 6;
    float mean = stat[t], rstd = stat[64 + t];
#pragma unroll 4
    for (int k = 0; k < 64; ++k) {
      int c = cg * 64 + k;
      float v = y1[c * 68 + t];
      v = (v - mean) * rstd * g1[c] + b1[c];
      y1[c * 68 + t] = gelu_f(v);
    }
  }
  __syncthreads();
  // ---- Phase B: pointwise GEMM 256x256, tile 8o x 8t ----
  int og = tid >> 3, tg = tid & 7;
  int o0 = og * 8, tb = tg * 8;
  float acc[8][8];
#pragma unroll
  for (int j = 0; j < 8; ++j) {
    float pv = pwb[o0 + j];
#pragma unroll
    for (int k = 0; k < 8; ++k) acc[j][k] = pv;
  }
#pragma unroll 1
  for (int c = 0; c < F_; c += 4) {
    float4 w4[8];
#pragma unroll
    for (int j = 0; j < 8; ++j)
      w4[j] = *(const float4*)(pww + (size_t)(o0 + j) * F_ + c);
#pragma unroll
    for (int cc = 0; cc < 4; ++cc) {
      float4 xlo = *(const float4*)&y1[(c + cc) * 68 + tb];
      float4 xhi = *(const float4*)&y1[(c + cc) * 68 + tb + 4];
#pragma unroll
      for (int j = 0; j < 8; ++j) {
        float w = cc == 0 ? w4[j].x : cc == 1 ? w4[j].y : cc == 2 ? w4[j].z : w4[j].w;
        acc[j][0] = fmaf(w, xlo.x, acc[j][0]);
        acc[j][1] = fmaf(w, xlo.y, acc[j][1]);
        acc[j][2] = fmaf(w, xlo.z, acc[j][2]);
        acc[j][3] = fmaf(w, xlo.w, acc[j][3]);
        acc[j][4] = fmaf(w, xhi.x, acc[j][4]);
        acc[j][5] = fmaf(w, xhi.y, acc[j][5]);
        acc[j][6] = fmaf(w, xhi.z, acc[j][6]);
        acc[j][7] = fmaf(w, xhi.w, acc[j][7]);
      }
    }
  }
  __syncthreads();
  // ---- Phase C: channel stats of y2 ----
  float* redC = y1;
#pragma unroll
  for (int k = 0; k < 8; ++k) {
    float s = 0.f, q = 0.f;
#pragma unroll
    for (int j = 0; j < 8; ++j) {
      float v = acc[j][k];
      s += v;
      q = fmaf(v, v, q);
    }
    redC[og * 65 + tb + k] = s;
    redC[32 * 65 + og * 65 + tb + k] = q;
  }
  __syncthreads();
  if (tid < 64) {
    float s = 0.f, q = 0.f;
#pragma unroll
    for (int g = 0; g < 32; ++g) {
      s += redC[g * 65 + tid];
      q += redC[32 * 65 + g * 65 + tid];
    }
    float mean = s * (1.f / 256.f);
    float var = q * (1.f / 256.f) - mean * mean;
    stat[tid] = mean;
    stat[64 + tid] = rsqrtf(var + 1e-5f);
  }
  __syncthreads();
  const float* hbr = h_in + ((size_t)b * F_) * T_ + t0;
#pragma unroll
  for (int j = 0; j < 8; ++j) {
    int o = o0 + j;
    float gg = g2[o], bb = b2[o];
    float4 r0 = *(const float4*)(hbr + (size_t)o * T_ + tb);
    float4 r1 = *(const float4*)(hbr + (size_t)o * T_ + tb + 4);
    float rr[8] = {r0.x, r0.y, r0.z, r0.w, r1.x, r1.y, r1.z, r1.w};
#pragma unroll
    for (int k = 0; k < 8; ++k) {
      int t = tb + k;
      float u = (acc[j][k] - stat[t]) * stat[64 + t] * gg + bb;
      acc[j][k] = rr[k] + gelu_f(u);
    }
  }
  if (!SPLIT_OUT) {
#pragma unroll
    for (int j = 0; j < 8; ++j) {
      int o = o0 + j;
      float4 w0 = make_float4(acc[j][0], acc[j][1], acc[j][2], acc[j][3]);
      float4 w1 = make_float4(acc[j][4], acc[j][5], acc[j][6], acc[j][7]);
      *(float4*)(h_out + ((size_t)b * F_ + o) * T_ + t0 + tb) = w0;
      *(float4*)(h_out + ((size_t)b * F_ + o) * T_ + t0 + tb + 4) = w1;
    }
  } else {
#pragma unroll
    for (int k = 0; k < 8; ++k) {
      int t = t0 + tb + k;
      float mv = mask[(size_t)b * T_ + t];
      ushort hv[8], lv[8];
#pragma unroll
      for (int j = 0; j < 8; ++j) {
        float v = acc[j][k] * mv;
        ushort h16 = f2bf(v);
        hv[j] = h16;
        lv[j] = f2bf(v - bf2f(h16));
      }
      size_t base = ((size_t)b * T_ + t) * F_ + o0;
      *(uint4*)(hi_out + base) = *(const uint4*)hv;
      *(uint4*)(lo_out + base) = *(const uint4*)lv;
    }
  }
}

// ---------------------------------------------------------------------------
// K-wsplit: proj_w fp32 -> bf16 hi/lo
// ---------------------------------------------------------------------------
__global__ void wsplit_k(const float* __restrict__ w,
                         ushort* __restrict__ whi, ushort* __restrict__ wlo,
                         int n) {
  int i = blockIdx.x * 256 + threadIdx.x;
  if (i >= n) return;
  float v = w[i];
  ushort h16 = f2bf(v);
  whi[i] = h16;
  wlo[i] = f2bf(v - bf2f(h16));
}

// ---------------------------------------------------------------------------
// K3: proj GEMM via split-bf16 MFMA + RQ spline + logdet
// grid (T/64, 12, B); block 256 (4 waves). Per block: M=232(pad256), N=64,
// K=256 staged in two 128-halves. Wave w owns m-tiles 4w..4w+3, ALL 4
// n-tiles (acc[4][4] = 64 VGPRs). A-frag loads per block: 256 (was 960).
// s-tile stored as bf16 -> LDS high-water 34.8 KB -> 4 blocks/CU.
// ---------------------------------------------------------------------------
__global__ __launch_bounds__(256, 4) void proj_spline_k(
    const ushort* __restrict__ h_hi, const ushort* __restrict__ h_lo,
    const float* __restrict__ x, const float* __restrict__ mask,
    const ushort* __restrict__ w_hi, const ushort* __restrict__ w_lo,
    const float* __restrict__ pb,
    float* __restrict__ out, float* __restrict__ logdet) {
  // union: B-staging (2 comps x 64 x 136 bf16 = 34816 B) / s-tile bf16 232x68
  __shared__ __align__(16) char smem[64 * 136 * 2 * 2];
  __shared__ float red[4];
  ushort* bh_lds = (ushort*)smem;             // [64][136]
  ushort* bl_lds = (ushort*)(smem + 64 * 136 * 2);
  ushort* s_lds = (ushort*)smem;              // [232][68] bf16 (after GEMM)

  int tid = threadIdx.x;
  int t0 = blockIdx.x * 64;
  int chunk = blockIdx.y;
  int b = blockIdx.z;
  int lane = tid & 63;
  int wid = tid >> 6;
  int col = lane & 15;
  int quad = lane >> 4;

  f32x4 acc[4][4];  // [mt][nt]
#pragma unroll
  for (int mt = 0; mt < 4; ++mt)
#pragma unroll
    for (int nt = 0; nt < 4; ++nt) acc[mt][nt] = (f32x4)(0.f);

  // A rows for this wave's 4 m-tiles (clamped; garbage rows masked at store)
  int rowA[4];
#pragma unroll
  for (int mt = 0; mt < 4; ++mt) {
    int r = chunk * 232 + (wid * 4 + mt) * 16 + col;
    rowA[mt] = r > 2783 ? 2783 : r;
  }

#pragma unroll 1
  for (int khalf = 0; khalf < 2; ++khalf) {
    // ---- stage B half: h_hi/h_lo [b][t0+t][khalf*128+k] -> lds [t][k] ----
#pragma unroll
    for (int p = 0; p < 4; ++p) {
      int idx = tid + p * 256;
      int row = idx >> 4;
      int u = idx & 15;
      size_t gs = ((size_t)(b * T_ + t0 + row)) * F_ + khalf * 128 + u * 8;
      *(uint4*)(bh_lds + row * 136 + u * 8) = *(const uint4*)(h_hi + gs);
      *(uint4*)(bl_lds + row * 136 + u * 8) = *(const uint4*)(h_lo + gs);
    }
    __syncthreads();
#pragma unroll
    for (int ks = 0; ks < 4; ++ks) {
      int kloc = ks * 32 + quad * 8;
      int kglob = khalf * 128 + kloc;
      // batch the wave's 8 A-fragment loads for this k-step
      s16x8 ah[4], al[4];
#pragma unroll
      for (int mt = 0; mt < 4; ++mt) {
        size_t off = (size_t)rowA[mt] * F_ + kglob;
        ah[mt] = *(const s16x8*)(w_hi + off);
        al[mt] = *(const s16x8*)(w_lo + off);
      }
#pragma unroll
      for (int nt = 0; nt < 4; ++nt) {
        s16x8 bh = *(const s16x8*)(bh_lds + (nt * 16 + col) * 136 + kloc);
        s16x8 bl = *(const s16x8*)(bl_lds + (nt * 16 + col) * 136 + kloc);
#pragma unroll
        for (int mt = 0; mt < 4; ++mt) {
          acc[mt][nt] = __builtin_amdgcn_mfma_f32_16x16x32_bf16(ah[mt], bh, acc[mt][nt], 0, 0, 0);
          acc[mt][nt] = __builtin_amdgcn_mfma_f32_16x16x32_bf16(al[mt], bh, acc[mt][nt], 0, 0, 0);
          acc[mt][nt] = __builtin_amdgcn_mfma_f32_16x16x32_bf16(ah[mt], bl, acc[mt][nt], 0, 0, 0);
        }
      }
    }
    __syncthreads();
  }
  // ---- write s-tile (bf16): s[local_row][t] = (acc + bias) * mask ----
  {
    float mv[4];
#pragma unroll
    for (int nt = 0; nt < 4; ++nt)
      mv[nt] = mask[(size_t)b * T_ + t0 + nt * 16 + col];
#pragma unroll
    for (int mt = 0; mt < 4; ++mt) {
#pragma unroll
      for (int r = 0; r < 4; ++r) {
        int local = (wid * 4 + mt) * 16 + quad * 4 + r;
        if (local < 232) {
          float bias = pb[chunk * 232 + local];
#pragma unroll
          for (int nt = 0; nt < 4; ++nt)
            s_lds[local * 68 + nt * 16 + col] =
                f2bf((acc[mt][nt][r] + bias) * mv[nt]);
        }
      }
    }
  }
  __syncthreads();
  // ---- spline: 8 ch x 64 t per block; 2 elements per thread ----
  float lad_sum = 0.f;
  int ch_i = tid >> 5, ti = tid & 31;
  int ch = chunk * 8 + ch_i;
#pragma unroll 1
  for (int pass = 0; pass < 2; ++pass) {
    int t = ti + pass * 32;
    float s[29];
#pragma unroll
    for (int j = 0; j < 29; ++j) s[j] = bf2f(s_lds[(ch_i * 29 + j) * 68 + t]);
    float xin = x[((size_t)b * C_ + HALF_ + ch) * T_ + t0 + t];
    float mval = mask[(size_t)b * T_ + t0 + t];
    float uw[10];
    float mx = -1e30f;
#pragma unroll
    for (int j = 0; j < 10; ++j) { uw[j] = s[j] * 0.0625f; mx = fmaxf(mx, uw[j]); }
    float ew[10]; float esum = 0.f;
#pragma unroll
    for (int j = 0; j < 10; ++j) { ew[j] = expf(uw[j] - mx); esum += ew[j]; }
    float inv = 1.f / esum;
    float cw[11];
    cw[0] = -5.f;
    float csum = 0.f;
#pragma unroll
    for (int j = 0; j < 9; ++j) {
      csum += fmaf(0.99f, ew[j] * inv, 0.001f);
      cw[j + 1] = fmaf(10.f, csum, -5.f);
    }
    cw[10] = 5.f;
    float uh[10]; mx = -1e30f;
#pragma unroll
    for (int j = 0; j < 10; ++j) { uh[j] = s[10 + j] * 0.0625f; mx = fmaxf(mx, uh[j]); }
    float eh[10]; esum = 0.f;
#pragma unroll
    for (int j = 0; j < 10; ++j) { eh[j] = expf(uh[j] - mx); esum += eh[j]; }
    inv = 1.f / esum;
    float chh[11];
    chh[0] = -5.f;
    csum = 0.f;
#pragma unroll
    for (int j = 0; j < 9; ++j) {
      csum += fmaf(0.99f, eh[j] * inv, 0.001f);
      chh[j + 1] = fmaf(10.f, csum, -5.f);
    }
    chh[10] = 5.f;
    float dv[11];
    dv[0] = 1.f; dv[10] = 1.f;
#pragma unroll
    for (int j = 1; j < 10; ++j) {
      float u = s[19 + j];
      float sp = (u > 15.f) ? u : log1pf(expf(u));
      dv[j] = 0.001f + sp;
    }
    float xc = fminf(fmaxf(xin, -5.f), 5.f);
    bool inside = (xin >= -5.f) && (xin <= 5.f);
    int idx = 0;
#pragma unroll
    for (int k = 1; k <= 10; ++k) idx += (xc >= cw[k]) ? 1 : 0;
    idx = idx > 9 ? 9 : idx;
    float in_cw = cw[0], in_w = cw[1] - cw[0];
    float in_ch = chh[0], in_h = chh[1] - chh[0];
    float d0 = dv[0], d1 = dv[1];
#pragma unroll
    for (int k = 1; k < 10; ++k) {
      bool sel = (idx == k);
      in_cw = sel ? cw[k] : in_cw;
      in_w = sel ? (cw[k + 1] - cw[k]) : in_w;
      in_ch = sel ? chh[k] : in_ch;
      in_h = sel ? (chh[k + 1] - chh[k]) : in_h;
      d0 = sel ? dv[k] : d0;
      d1 = sel ? dv[k + 1] : d1;
    }
    float theta = (xc - in_cw) / in_w;
    float delta = in_h / in_w;
    float omt = 1.f - theta;
    float t1m = theta * omt;
    float th2 = theta * theta;
    float denom = delta + (d0 + d1 - 2.f * delta) * t1m;
    float num = in_h * (delta * th2 + d0 * t1m);
    float outv = in_ch + num / denom;
    float dnum = delta * delta * (d1 * th2 + 2.f * delta * t1m + d0 * omt * omt);
    float lad = logf(dnum) - 2.f * logf(denom);
    float res = inside ? outv : xin;
    float ladv = inside ? lad : 0.f;
    out[((size_t)b * C_ + HALF_ + ch) * T_ + t0 + t] = res * mval;
    lad_sum += ladv * mval;
  }
#pragma unroll
  for (int off = 32; off > 0; off >>= 1)
    lad_sum += __shfl_down(lad_sum, off, 64);
  if ((tid & 63) == 0) red[tid >> 6] = lad_sum;
  __syncthreads();
  if (tid == 0)
    atomicAdd(logdet + b, red[0] + red[1] + red[2] + red[3]);
}

// ---------------------------------------------------------------------------
// K4: out[:, :96, :] = x0 * mask
// ---------------------------------------------------------------------------
__global__ void copy_x0_k(const float* __restrict__ x,
                          const float* __restrict__ mask,
                          float* __restrict__ out) {
  int i = blockIdx.x * 256 + threadIdx.x;
  int b = i / (HALF_ * T_ / 4);
  int r = i - b * (HALF_ * T_ / 4);
  int t4 = r & (T_ / 4 - 1);
  float4 v = ((const float4*)(x + (size_t)b * C_ * T_))[r];
  float4 m = ((const float4*)(mask + (size_t)b * T_))[t4];
  v.x *= m.x; v.y *= m.y; v.z *= m.z; v.w *= m.w;
  ((float4*)(out + (size_t)b * C_ * T_))[r] = v;
}

extern "C" void kernel_launch(void* const* d_in, const int* in_sizes, int n_in,
                              void* d_out, int out_size, void* d_ws, size_t ws_size,
                              hipStream_t stream) {
  const float* x      = (const float*)d_in[0];
  const float* mask   = (const float*)d_in[1];
  const float* pre_w  = (const float*)d_in[2];
  const float* pre_b  = (const float*)d_in[3];
  const float* dw_w   = (const float*)d_in[4];
  const float* dw_b   = (const float*)d_in[5];
  const float* pw_w   = (const float*)d_in[6];
  const float* pw_b   = (const float*)d_in[7];
  const float* g1     = (const float*)d_in[8];
  const float* b1     = (const float*)d_in[9];
  const float* g2     = (const float*)d_in[10];
  const float* b2     = (const float*)d_in[11];
  const float* proj_w = (const float*)d_in[12];
  const float* proj_b = (const float*)d_in[13];
  float* out = (float*)d_out;
  float* logdet = out + (size_t)B_ * C_ * T_;
  float* hA = (float*)d_ws;                      // 33.55 MB
  float* hB = hA + (size_t)B_ * F_ * T_;         // 33.55 MB
  ushort* h_hi = (ushort*)hB;
  ushort* h_lo = h_hi + (size_t)B_ * T_ * F_;
  ushort* w_hi = (ushort*)hA;
  ushort* w_lo = w_hi + 2784 * 256;

  hipMemsetAsync(logdet, 0, B_ * sizeof(float), stream);
  pre_gemm_k<<<dim3(T_ / 256, F_ / 8, B_), 256, 0, stream>>>(x, pre_w, pre_b, hA);
  layer_k<false><<<dim3(T_ / 64, B_), 256, 0, stream>>>(hA, hB, nullptr, nullptr,
      mask, dw_w, dw_b, g1, b1, pw_w, pw_b, g2, b2, 1);
  layer_k<false><<<dim3(T_ / 64, B_), 256, 0, stream>>>(hB, hA, nullptr, nullptr,
      mask, dw_w + F_ * 3, dw_b + F_, g1 + F_, b1 + F_,
      pw_w + F_ * F_, pw_b + F_, g2 + F_, b2 + F_, 3);
  layer_k<true><<<dim3(T_ / 64, B_), 256, 0, stream>>>(hA, nullptr, h_hi, h_lo,
      mask, dw_w + 2 * F_ * 3, dw_b + 2 * F_, g1 + 2 * F_, b1 + 2 * F_,
      pw_w + 2 * F_ * F_, pw_b + 2 * F_, g2 + 2 * F_, b2 + 2 * F_, 9);
  wsplit_k<<<dim3((2784 * 256 + 255) / 256), 256, 0, stream>>>(proj_w, w_hi, w_lo,
      2784 * 256);
  copy_x0_k<<<dim3(B_ * HALF_ * T_ / 4 / 256), 256, 0, stream>>>(x, mask, out);
  proj_spline_k<<<dim3(T_ / 64, 12, B_), 256, 0, stream>>>(h_hi, h_lo, x, mask,
      w_hi, w_lo, proj_b, out, logdet);
}

// Round 4
// 591.792 us; speedup vs baseline: 2.0945x; 1.5434x over previous
//
#include <hip/hip_runtime.h>

#define B_ 16
#define C_ 192
#define T_ 2048
#define F_ 256
#define HALF_ 96

typedef short s16x8 __attribute__((ext_vector_type(8)));
typedef float f32x4 __attribute__((ext_vector_type(4)));
typedef unsigned short ushort;

union U8 { uint4 v; ushort u[8]; };

__device__ __forceinline__ float gelu_f(float x) {
  return 0.5f * x * (1.f + erff(x * 0.70710678118654752f));
}
__device__ __forceinline__ ushort f2bf(float f) {
  unsigned u = __float_as_uint(f);
  unsigned r = u + 0x7fff + ((u >> 16) & 1);
  return (ushort)(r >> 16);
}
__device__ __forceinline__ float bf2f(ushort h) {
  return __uint_as_float(((unsigned)h) << 16);
}

// ---------------------------------------------------------------------------
// K1: h[b,f,t] = pre_w[f,:] @ x0[b,:,t] + pre_b[f]  (bf16 out)
// ---------------------------------------------------------------------------
__global__ void pre_gemm_k(const float* __restrict__ x,
                           const float* __restrict__ pw,
                           const float* __restrict__ pb,
                           ushort* __restrict__ h) {
  int t = blockIdx.x * 256 + threadIdx.x;
  int f0 = blockIdx.y * 8;
  int b = blockIdx.z;
  float acc[8];
#pragma unroll
  for (int j = 0; j < 8; ++j) acc[j] = pb[f0 + j];
  const float* xp = x + ((size_t)b * C_) * T_ + t;
  const float* wp = pw + (size_t)f0 * HALF_;
#pragma unroll 4
  for (int c = 0; c < HALF_; ++c) {
    float xv = xp[(size_t)c * T_];
#pragma unroll
    for (int j = 0; j < 8; ++j)
      acc[j] = fmaf(wp[j * HALF_ + c], xv, acc[j]);
  }
  ushort* hp = h + ((size_t)b * F_ + f0) * T_ + t;
#pragma unroll
  for (int j = 0; j < 8; ++j) hp[(size_t)j * T_] = f2bf(acc[j]);
}

// ---------------------------------------------------------------------------
// K-wsplit: fp32 -> bf16 hi/lo
// ---------------------------------------------------------------------------
__global__ void wsplit_k(const float* __restrict__ w,
                         ushort* __restrict__ whi, ushort* __restrict__ wlo,
                         int n) {
  int i = blockIdx.x * 256 + threadIdx.x;
  if (i >= n) return;
  float v = w[i];
  ushort h16 = f2bf(v);
  whi[i] = h16;
  wlo[i] = f2bf(v - bf2f(h16));
}

// ---------------------------------------------------------------------------
// K2: one layer, MFMA pointwise GEMM.
//   conv(bf16 h_in * mask) -> cnorm -> gelu -> y1 (bf16, LDS [t][c])
//   y2 = pw(hi/lo MFMA) @ y1 -> cnorm -> gelu -> + h_in
//   TRANS_OUT=false: h_out bf16 [b][c][t];  true: (h*mask) bf16 [b][t][c]
// ---------------------------------------------------------------------------
template <bool TRANS_OUT>
__global__ __launch_bounds__(256, 3) void layer_mfma_k(
    const ushort* __restrict__ h_in,
    ushort* __restrict__ h_out,        // !TRANS
    ushort* __restrict__ hT_out,       // TRANS
    const float* __restrict__ mask,
    const float* __restrict__ dww, const float* __restrict__ dwb,
    const float* __restrict__ g1, const float* __restrict__ b1,
    const ushort* __restrict__ pwh, const ushort* __restrict__ pwl,
    const float* __restrict__ pwb,
    const float* __restrict__ g2, const float* __restrict__ b2,
    int dil) {
  __shared__ ushort y1b[64 * 264];       // [t][c] bf16, 33.8 KB
  __shared__ float scratch[2048];        // partials (conv: 512 used; epi: 2048)
  __shared__ float stat[2 * 64];
  int tid = threadIdx.x;
  int b = blockIdx.y;
  int t0 = blockIdx.x * 64;

  // ---- Phase A: depthwise conv + stats (exact v), write bf16 to LDS ----
  {
    int t = tid & 63, cg = tid >> 6;
    int tz = t0 + t;
    int tm = tz - dil, tp = tz + dil;
    bool vm = (tm >= 0), vp = (tp < T_);
    float mm = vm ? mask[b * T_ + tm] : 0.f;
    float mz = mask[b * T_ + tz];
    float mp = vp ? mask[b * T_ + tp] : 0.f;
    const ushort* hb = h_in + ((size_t)b * F_) * T_;
    float s = 0.f, q = 0.f;
#pragma unroll 1
    for (int g = 0; g < 8; ++g) {
      U8 pk;
#pragma unroll
      for (int i = 0; i < 8; ++i) {
        int c = cg * 64 + g * 8 + i;
        const ushort* hr = hb + (size_t)c * T_;
        float v0 = vm ? bf2f(hr[tm]) * mm : 0.f;
        float v1 = bf2f(hr[tz]) * mz;
        float v2 = vp ? bf2f(hr[tp]) * mp : 0.f;
        float v = fmaf(dww[c * 3], v0,
                  fmaf(dww[c * 3 + 1], v1,
                  fmaf(dww[c * 3 + 2], v2, dwb[c])));
        pk.u[i] = f2bf(v);
        s += v;
        q = fmaf(v, v, q);
      }
      *(uint4*)&y1b[t * 264 + cg * 64 + g * 8] = pk.v;
    }
    scratch[cg * 64 + t] = s;
    scratch[256 + cg * 64 + t] = q;
  }
  __syncthreads();
  if (tid < 64) {
    float s = scratch[tid] + scratch[64 + tid] + scratch[128 + tid] + scratch[192 + tid];
    float q = scratch[256 + tid] + scratch[320 + tid] + scratch[384 + tid] + scratch[448 + tid];
    float mean = s * (1.f / 256.f);
    float var = q * (1.f / 256.f) - mean * mean;
    stat[tid] = mean;
    stat[64 + tid] = rsqrtf(var + 1e-5f);
  }
  __syncthreads();
  // ---- Phase A3: normalize + gelu in place ----
  {
    int t = tid & 63, cg = tid >> 6;
    float mean = stat[t], rstd = stat[64 + t];
#pragma unroll 1
    for (int g = 0; g < 8; ++g) {
      U8 pk;
      pk.v = *(const uint4*)&y1b[t * 264 + cg * 64 + g * 8];
#pragma unroll
      for (int i = 0; i < 8; ++i) {
        int c = cg * 64 + g * 8 + i;
        float v = (bf2f(pk.u[i]) - mean) * rstd * g1[c] + b1[c];
        pk.u[i] = f2bf(gelu_f(v));
      }
      *(uint4*)&y1b[t * 264 + cg * 64 + g * 8] = pk.v;
    }
  }
  __syncthreads();
  // ---- Phase B: MFMA GEMM: W(256x256, hi/lo) @ y1(256k x 64t) ----
  int lane = tid & 63;
  int wid = tid >> 6;
  int col = lane & 15;
  int quad = lane >> 4;
  f32x4 acc[4][4];  // [mt][nt]
#pragma unroll
  for (int mt = 0; mt < 4; ++mt)
#pragma unroll
    for (int nt = 0; nt < 4; ++nt) acc[mt][nt] = (f32x4)(0.f);
  int rowA[4];
#pragma unroll
  for (int mt = 0; mt < 4; ++mt) rowA[mt] = (wid * 4 + mt) * 16 + col;

#pragma unroll 1
  for (int ks = 0; ks < 8; ++ks) {
    int kloc = ks * 32 + quad * 8;
    s16x8 ah[4], al[4];
#pragma unroll
    for (int mt = 0; mt < 4; ++mt) {
      size_t off = (size_t)rowA[mt] * F_ + kloc;
      ah[mt] = *(const s16x8*)(pwh + off);
      al[mt] = *(const s16x8*)(pwl + off);
    }
#pragma unroll
    for (int nt = 0; nt < 4; ++nt) {
      s16x8 bv = *(const s16x8*)(y1b + (nt * 16 + col) * 264 + kloc);
#pragma unroll
      for (int mt = 0; mt < 4; ++mt) {
        acc[mt][nt] = __builtin_amdgcn_mfma_f32_16x16x32_bf16(ah[mt], bv, acc[mt][nt], 0, 0, 0);
        acc[mt][nt] = __builtin_amdgcn_mfma_f32_16x16x32_bf16(al[mt], bv, acc[mt][nt], 0, 0, 0);
      }
    }
  }
  __syncthreads();
  // ---- epilogue: bias, per-t stats over 256 channels ----
  float pwbv[4][4];
#pragma unroll
  for (int mt = 0; mt < 4; ++mt)
#pragma unroll
    for (int r = 0; r < 4; ++r)
      pwbv[mt][r] = pwb[(wid * 4 + mt) * 16 + quad * 4 + r];
#pragma unroll
  for (int nt = 0; nt < 4; ++nt) {
    float s = 0.f, q = 0.f;
#pragma unroll
    for (int mt = 0; mt < 4; ++mt)
#pragma unroll
      for (int r = 0; r < 4; ++r) {
        float v = acc[mt][nt][r] + pwbv[mt][r];
        acc[mt][nt][r] = v;
        s += v;
        q = fmaf(v, v, q);
      }
    int pcol = (wid * 4 + quad) * 64 + nt * 16 + col;
    scratch[pcol] = s;
    scratch[1024 + pcol] = q;
  }
  __syncthreads();
  if (tid < 64) {
    float s = 0.f, q = 0.f;
#pragma unroll
    for (int p = 0; p < 16; ++p) {
      s += scratch[p * 64 + tid];
      q += scratch[1024 + p * 64 + tid];
    }
    float mean = s * (1.f / 256.f);
    float var = q * (1.f / 256.f) - mean * mean;
    stat[tid] = mean;
    stat[64 + tid] = rsqrtf(var + 1e-5f);
  }
  __syncthreads();
  // ---- normalize + gelu + residual + store ----
  float g2v[4][4], b2v[4][4];
#pragma unroll
  for (int mt = 0; mt < 4; ++mt)
#pragma unroll
    for (int r = 0; r < 4; ++r) {
      int o = (wid * 4 + mt) * 16 + quad * 4 + r;
      g2v[mt][r] = g2[o];
      b2v[mt][r] = b2[o];
    }
#pragma unroll
  for (int nt = 0; nt < 4; ++nt) {
    int t = t0 + nt * 16 + col;
    float mean = stat[nt * 16 + col], rstd = stat[64 + nt * 16 + col];
    float mval = TRANS_OUT ? mask[(size_t)b * T_ + t] : 0.f;
#pragma unroll
    for (int mt = 0; mt < 4; ++mt) {
      ushort tmp4[4];
#pragma unroll
      for (int r = 0; r < 4; ++r) {
        int o = (wid * 4 + mt) * 16 + quad * 4 + r;
        float u = (acc[mt][nt][r] - mean) * rstd * g2v[mt][r] + b2v[mt][r];
        float hv = bf2f(h_in[((size_t)b * F_ + o) * T_ + t]) + gelu_f(u);
        if (!TRANS_OUT)
          h_out[((size_t)b * F_ + o) * T_ + t] = f2bf(hv);
        else
          tmp4[r] = f2bf(hv * mval);
      }
      if (TRANS_OUT) {
        int ob = (wid * 4 + mt) * 16 + quad * 4;
        *(uint2*)(hT_out + ((size_t)b * T_ + t) * F_ + ob) = *(const uint2*)tmp4;
      }
    }
  }
}

// ---------------------------------------------------------------------------
// K3: proj GEMM (split-bf16 weights x single-bf16 h) + RQ spline + logdet
// grid (T/64, 12, B); block 256. M=232(pad256), N=64, K=256 staged once.
// ---------------------------------------------------------------------------
__global__ __launch_bounds__(256, 4) void proj_spline_k(
    const ushort* __restrict__ hT,
    const float* __restrict__ x, const float* __restrict__ mask,
    const ushort* __restrict__ w_hi, const ushort* __restrict__ w_lo,
    const float* __restrict__ pb,
    float* __restrict__ out, float* __restrict__ logdet) {
  __shared__ __align__(16) ushort bsm[64 * 264];   // B [t][k] bf16; 33.8 KB
  __shared__ float red[4];
  ushort* s_lds = bsm;                             // s-tile [232][68] overlay

  int tid = threadIdx.x;
  int t0 = blockIdx.x * 64;
  int chunk = blockIdx.y;
  int b = blockIdx.z;
  int lane = tid & 63;
  int wid = tid >> 6;
  int col = lane & 15;
  int quad = lane >> 4;

  // ---- stage B: full K=256 for 64 t (2048 16B-chunks, 8 per thread) ----
#pragma unroll
  for (int p = 0; p < 8; ++p) {
    int idx = tid + p * 256;
    int row = idx >> 5;
    int u = idx & 31;
    *(uint4*)(bsm + row * 264 + u * 8) =
        *(const uint4*)(hT + ((size_t)(b * T_ + t0 + row)) * F_ + u * 8);
  }

  f32x4 acc[4][4];
#pragma unroll
  for (int mt = 0; mt < 4; ++mt)
#pragma unroll
    for (int nt = 0; nt < 4; ++nt) acc[mt][nt] = (f32x4)(0.f);
  int rowA[4];
#pragma unroll
  for (int mt = 0; mt < 4; ++mt) {
    int r = chunk * 232 + (wid * 4 + mt) * 16 + col;
    rowA[mt] = r > 2783 ? 2783 : r;
  }
  __syncthreads();
#pragma unroll 1
  for (int ks = 0; ks < 8; ++ks) {
    int kloc = ks * 32 + quad * 8;
    s16x8 ah[4], al[4];
#pragma unroll
    for (int mt = 0; mt < 4; ++mt) {
      size_t off = (size_t)rowA[mt] * F_ + kloc;
      ah[mt] = *(const s16x8*)(w_hi + off);
      al[mt] = *(const s16x8*)(w_lo + off);
    }
#pragma unroll
    for (int nt = 0; nt < 4; ++nt) {
      s16x8 bv = *(const s16x8*)(bsm + (nt * 16 + col) * 264 + kloc);
#pragma unroll
      for (int mt = 0; mt < 4; ++mt) {
        acc[mt][nt] = __builtin_amdgcn_mfma_f32_16x16x32_bf16(ah[mt], bv, acc[mt][nt], 0, 0, 0);
        acc[mt][nt] = __builtin_amdgcn_mfma_f32_16x16x32_bf16(al[mt], bv, acc[mt][nt], 0, 0, 0);
      }
    }
  }
  __syncthreads();
  // ---- write s-tile (bf16): s[local][t] = (acc + bias) * mask ----
  {
    float mv[4];
#pragma unroll
    for (int nt = 0; nt < 4; ++nt)
      mv[nt] = mask[(size_t)b * T_ + t0 + nt * 16 + col];
#pragma unroll
    for (int mt = 0; mt < 4; ++mt) {
#pragma unroll
      for (int r = 0; r < 4; ++r) {
        int local = (wid * 4 + mt) * 16 + quad * 4 + r;
        if (local < 232) {
          float bias = pb[chunk * 232 + local];
#pragma unroll
          for (int nt = 0; nt < 4; ++nt)
            s_lds[local * 68 + nt * 16 + col] =
                f2bf((acc[mt][nt][r] + bias) * mv[nt]);
        }
      }
    }
  }
  __syncthreads();
  // ---- spline: 8 ch x 64 t per block; 2 elements per thread ----
  float lad_sum = 0.f;
  int ch_i = tid >> 5, ti = tid & 31;
  int ch = chunk * 8 + ch_i;
#pragma unroll 1
  for (int pass = 0; pass < 2; ++pass) {
    int t = ti + pass * 32;
    float s[29];
#pragma unroll
    for (int j = 0; j < 29; ++j) s[j] = bf2f(s_lds[(ch_i * 29 + j) * 68 + t]);
    float xin = x[((size_t)b * C_ + HALF_ + ch) * T_ + t0 + t];
    float mval = mask[(size_t)b * T_ + t0 + t];
    float uw[10];
    float mx = -1e30f;
#pragma unroll
    for (int j = 0; j < 10; ++j) { uw[j] = s[j] * 0.0625f; mx = fmaxf(mx, uw[j]); }
    float ew[10]; float esum = 0.f;
#pragma unroll
    for (int j = 0; j < 10; ++j) { ew[j] = __expf(uw[j] - mx); esum += ew[j]; }
    float inv = 1.f / esum;
    float cw[11];
    cw[0] = -5.f;
    float csum = 0.f;
#pragma unroll
    for (int j = 0; j < 9; ++j) {
      csum += fmaf(0.99f, ew[j] * inv, 0.001f);
      cw[j + 1] = fmaf(10.f, csum, -5.f);
    }
    cw[10] = 5.f;
    float uh[10]; mx = -1e30f;
#pragma unroll
    for (int j = 0; j < 10; ++j) { uh[j] = s[10 + j] * 0.0625f; mx = fmaxf(mx, uh[j]); }
    float eh[10]; esum = 0.f;
#pragma unroll
    for (int j = 0; j < 10; ++j) { eh[j] = __expf(uh[j] - mx); esum += eh[j]; }
    inv = 1.f / esum;
    float chh[11];
    chh[0] = -5.f;
    csum = 0.f;
#pragma unroll
    for (int j = 0; j < 9; ++j) {
      csum += fmaf(0.99f, eh[j] * inv, 0.001f);
      chh[j + 1] = fmaf(10.f, csum, -5.f);
    }
    chh[10] = 5.f;
    float dv[11];
    dv[0] = 1.f; dv[10] = 1.f;
#pragma unroll
    for (int j = 1; j < 10; ++j) {
      float u = s[19 + j];
      float sp = (u > 15.f) ? u : __logf(1.f + __expf(u));
      dv[j] = 0.001f + sp;
    }
    float xc = fminf(fmaxf(xin, -5.f), 5.f);
    bool inside = (xin >= -5.f) && (xin <= 5.f);
    int idx = 0;
#pragma unroll
    for (int k = 1; k <= 10; ++k) idx += (xc >= cw[k]) ? 1 : 0;
    idx = idx > 9 ? 9 : idx;
    float in_cw = cw[0], in_w = cw[1] - cw[0];
    float in_ch = chh[0], in_h = chh[1] - chh[0];
    float d0 = dv[0], d1 = dv[1];
#pragma unroll
    for (int k = 1; k < 10; ++k) {
      bool sel = (idx == k);
      in_cw = sel ? cw[k] : in_cw;
      in_w = sel ? (cw[k + 1] - cw[k]) : in_w;
      in_ch = sel ? chh[k] : in_ch;
      in_h = sel ? (chh[k + 1] - chh[k]) : in_h;
      d0 = sel ? dv[k] : d0;
      d1 = sel ? dv[k + 1] : d1;
    }
    float theta = (xc - in_cw) / in_w;
    float delta = in_h / in_w;
    float omt = 1.f - theta;
    float t1m = theta * omt;
    float th2 = theta * theta;
    float denom = delta + (d0 + d1 - 2.f * delta) * t1m;
    float num = in_h * (delta * th2 + d0 * t1m);
    float outv = in_ch + num / denom;
    float dnum = delta * delta * (d1 * th2 + 2.f * delta * t1m + d0 * omt * omt);
    float lad = __logf(dnum) - 2.f * __logf(denom);
    float res = inside ? outv : xin;
    float ladv = inside ? lad : 0.f;
    out[((size_t)b * C_ + HALF_ + ch) * T_ + t0 + t] = res * mval;
    lad_sum += ladv * mval;
  }
#pragma unroll
  for (int off = 32; off > 0; off >>= 1)
    lad_sum += __shfl_down(lad_sum, off, 64);
  if ((tid & 63) == 0) red[tid >> 6] = lad_sum;
  __syncthreads();
  if (tid == 0)
    atomicAdd(logdet + b, red[0] + red[1] + red[2] + red[3]);
}

// ---------------------------------------------------------------------------
// K4: out[:, :96, :] = x0 * mask
// ---------------------------------------------------------------------------
__global__ void copy_x0_k(const float* __restrict__ x,
                          const float* __restrict__ mask,
                          float* __restrict__ out) {
  int i = blockIdx.x * 256 + threadIdx.x;
  int b = i / (HALF_ * T_ / 4);
  int r = i - b * (HALF_ * T_ / 4);
  int t4 = r & (T_ / 4 - 1);
  float4 v = ((const float4*)(x + (size_t)b * C_ * T_))[r];
  float4 m = ((const float4*)(mask + (size_t)b * T_))[t4];
  v.x *= m.x; v.y *= m.y; v.z *= m.z; v.w *= m.w;
  ((float4*)(out + (size_t)b * C_ * T_))[r] = v;
}

extern "C" void kernel_launch(void* const* d_in, const int* in_sizes, int n_in,
                              void* d_out, int out_size, void* d_ws, size_t ws_size,
                              hipStream_t stream) {
  const float* x      = (const float*)d_in[0];
  const float* mask   = (const float*)d_in[1];
  const float* pre_w  = (const float*)d_in[2];
  const float* pre_b  = (const float*)d_in[3];
  const float* dw_w   = (const float*)d_in[4];
  const float* dw_b   = (const float*)d_in[5];
  const float* pw_w   = (const float*)d_in[6];
  const float* pw_b   = (const float*)d_in[7];
  const float* g1     = (const float*)d_in[8];
  const float* b1     = (const float*)d_in[9];
  const float* g2     = (const float*)d_in[10];
  const float* b2     = (const float*)d_in[11];
  const float* proj_w = (const float*)d_in[12];
  const float* proj_b = (const float*)d_in[13];
  float* out = (float*)d_out;
  float* logdet = out + (size_t)B_ * C_ * T_;

  // ws layout (ws >= 67.1 MB known-good):
  //   region1: hP0 (16.78 MB) + hP1 (16.78 MB)
  //   region2: hT (16.78 MB) + w_hi/w_lo (2x1.43) + pwh/pwl (2x0.39)
  const size_t HSZ = (size_t)B_ * F_ * T_;   // 8388608 elems
  ushort* hP0 = (ushort*)d_ws;
  ushort* hP1 = hP0 + HSZ;
  ushort* hT  = hP1 + HSZ;
  ushort* w_hi = hT + HSZ;
  ushort* w_lo = w_hi + 2784 * 256;
  ushort* pwh  = w_lo + 2784 * 256;
  ushort* pwl  = pwh + 3 * F_ * F_;

  hipMemsetAsync(logdet, 0, B_ * sizeof(float), stream);
  wsplit_k<<<dim3((2784 * 256 + 255) / 256), 256, 0, stream>>>(proj_w, w_hi, w_lo,
      2784 * 256);
  wsplit_k<<<dim3((3 * F_ * F_ + 255) / 256), 256, 0, stream>>>(pw_w, pwh, pwl,
      3 * F_ * F_);
  pre_gemm_k<<<dim3(T_ / 256, F_ / 8, B_), 256, 0, stream>>>(x, pre_w, pre_b, hP0);
  layer_mfma_k<false><<<dim3(T_ / 64, B_), 256, 0, stream>>>(hP0, hP1, nullptr,
      mask, dw_w, dw_b, g1, b1, pwh, pwl, pw_b, g2, b2, 1);
  layer_mfma_k<false><<<dim3(T_ / 64, B_), 256, 0, stream>>>(hP1, hP0, nullptr,
      mask, dw_w + F_ * 3, dw_b + F_, g1 + F_, b1 + F_,
      pwh + F_ * F_, pwl + F_ * F_, pw_b + F_, g2 + F_, b2 + F_, 3);
  layer_mfma_k<true><<<dim3(T_ / 64, B_), 256, 0, stream>>>(hP0, nullptr, hT,
      mask, dw_w + 2 * F_ * 3, dw_b + 2 * F_, g1 + 2 * F_, b1 + 2 * F_,
      pwh + 2 * F_ * F_, pwl + 2 * F_ * F_, pw_b + 2 * F_, g2 + 2 * F_,
      b2 + 2 * F_, 9);
  copy_x0_k<<<dim3(B_ * HALF_ * T_ / 4 / 256), 256, 0, stream>>>(x, mask, out);
  proj_spline_k<<<dim3(T_ / 64, 12, B_), 256, 0, stream>>>(hT, x, mask,
      w_hi, w_lo, proj_b, out, logdet);
}